// Round 3
// baseline (1039.532 us; speedup 1.0000x reference)
//
#include <hip/hip_runtime.h>
#include <hip/hip_bf16.h>

#define BB 2
#define CC 512
#define HH 14
#define WW 14
#define PP 196
#define NSEQ 8
#define FSTR 16          // flag stride (uints) -> one cache line per cell

// ---------------------------------------------------------------------------
// prep: gemm_a (224 WGs) + transpose_wh (256 WGs) + flag zero (1 WG)
// ---------------------------------------------------------------------------
__global__ __launch_bounds__(256) void prep(
    const float* __restrict__ Wx, const float* __restrict__ X,
    const float* __restrict__ b_in, const float* __restrict__ Wh,
    float* __restrict__ A, float* __restrict__ WhT, unsigned* __restrict__ flags) {
    __shared__ float Ws[32][33], Xs[32][33];
    int bid = blockIdx.x;
    int t = threadIdx.x;
    if (bid < 224) {
        // A[b][p][c] = sum_k Wx[c][k] * X[b][k][p] + b_in[c]
        int z = bid / 112, rem = bid % 112;
        int c0 = (rem % 16) * 32, p0 = (rem / 16) * 32;
        int tx = t % 32, ty = t / 32;
        int pl = (t % 16) * 2, cl = (t / 16) * 2;
        float acc[2][2] = {{0.f,0.f},{0.f,0.f}};
        for (int k0 = 0; k0 < CC; k0 += 32) {
            #pragma unroll
            for (int r = 0; r < 4; ++r)
                Ws[ty + 8*r][tx] = Wx[(size_t)(c0 + ty + 8*r) * CC + k0 + tx];
            #pragma unroll
            for (int r = 0; r < 4; ++r) {
                int p = p0 + tx, k = k0 + ty + 8*r;
                Xs[ty + 8*r][tx] = (p < PP) ? X[((size_t)z * CC + k) * PP + p] : 0.f;
            }
            __syncthreads();
            #pragma unroll
            for (int k = 0; k < 32; ++k) {
                float w0 = Ws[cl][k], w1 = Ws[cl+1][k];
                float x0 = Xs[k][pl], x1 = Xs[k][pl+1];
                acc[0][0] += w0*x0; acc[0][1] += w0*x1;
                acc[1][0] += w1*x0; acc[1][1] += w1*x1;
            }
            __syncthreads();
        }
        #pragma unroll
        for (int i = 0; i < 2; ++i)
            #pragma unroll
            for (int j = 0; j < 2; ++j) {
                int c = c0 + cl + i, p = p0 + pl + j;
                if (p < PP) A[((size_t)z * PP + p) * CC + c] = acc[i][j] + b_in[c];
            }
    } else if (bid < 480) {
        int tid = bid - 224;
        int c0 = (tid % 16) * 32, k0 = (tid / 16) * 32;
        int tx = t % 32, ty = t / 32;
        #pragma unroll
        for (int r = 0; r < 4; ++r)
            Ws[ty + 8*r][tx] = Wh[(size_t)(c0 + ty + 8*r) * CC + k0 + tx];
        __syncthreads();
        #pragma unroll
        for (int r = 0; r < 4; ++r)
            WhT[(size_t)(k0 + ty + 8*r) * CC + c0 + tx] = Ws[tx][ty + 8*r];
    } else {
        if (t < PP) flags[t * FSTR] = 0u;
    }
}

// ---------------------------------------------------------------------------
// dataflow: 392 WGs of 512 threads. WG = (cell, channel-half). wave = seq for
// the window phases; all 8 waves cooperate on the 512x512x8 matvec mini-GEMM.
// ---------------------------------------------------------------------------
__device__ __forceinline__ void wave_wait2(unsigned* f, int lane) {
    while (true) {
        unsigned p = 0;
        if (lane == 0) p = atomicAdd(f, 0u);
        p = (unsigned)__shfl((int)p, 0, 64);
        if (p >= 2u) break;
        __builtin_amdgcn_s_sleep(4);
    }
}

__device__ __forceinline__ void do_pixel8(const float* __restrict__ Uq,
                                          const float* __restrict__ Eq,
                                          int cb, const float* ar, const float* er,
                                          float* hacc) {
    const float4* up = (const float4*)(Uq + cb);
    const float4* ep = (const float4*)(Eq + cb);
    float4 u0 = up[0], u1 = up[64];
    float4 e0 = ep[0], e1 = ep[64];
    float uu[8] = {u0.x,u0.y,u0.z,u0.w,u1.x,u1.y,u1.z,u1.w};
    float ee[8] = {e0.x,e0.y,e0.z,e0.w,e1.x,e1.y,e1.z,e1.w};
    float ds = 0.f, tl[8];
    #pragma unroll
    for (int j = 0; j < 8; ++j) {
        float sv = ar[j] + uu[j];       // a + U
        float pv = er[j] * ee[j];       // exp(a+U)
        ds += fmaxf(pv, 1.0f);          // exp(relu(a+U))
        tl[j] = fmaxf(sv, 0.0f) * pv;   // z * exp(z)
    }
    #pragma unroll
    for (int off = 32; off; off >>= 1) ds += __shfl_xor(ds, off, 64);
    float rd = 1.0f / ds;
    #pragma unroll
    for (int j = 0; j < 8; ++j) hacc[j] += tl[j] * rd;
}

__global__ __launch_bounds__(512, 4) void rnn_dataflow(
    const float* __restrict__ A, const float* __restrict__ WhT,
    float* __restrict__ U, float* __restrict__ EU,
    float* __restrict__ Hst, unsigned* __restrict__ flags) {
    __shared__ float hS[NSEQ][520];     // h per seq (row-padded)
    __shared__ float hT[CC][8];         // transposed: all 8 seqs per k
    int bid = blockIdx.x;
    int half = (bid >= PP) ? 1 : 0;
    int cell = half ? bid - PP : bid;
    int px = cell / WW, py = cell % WW;
    int t = threadIdx.x, wave = t >> 6, lane = t & 63;
    int s = wave, m = s >> 1, b = s & 1;
    int fi = (m & 2) ? (HH-1-px) : px;
    int fj = (m & 1) ? (WW-1-py) : py;
    int cb = lane * 4;

    // per-lane a / exp(a) for this seq's scan-cell (direct global, no LDS)
    const float* acur = A + ((size_t)b * PP + fi * WW + fj) * CC;
    float4 a0 = *(const float4*)(acur + cb);
    float4 a1 = *(const float4*)(acur + cb + 256);
    float ar[8] = {a0.x,a0.y,a0.z,a0.w,a1.x,a1.y,a1.z,a1.w};
    float er[8];
    #pragma unroll
    for (int j = 0; j < 8; ++j) er[j] = expf(ar[j]);
    float hacc[8] = {0.f,0.f,0.f,0.f,0.f,0.f,0.f,0.f};

    const float* Ub = U  + (size_t)s * PP * CC;
    const float* Eb = EU + (size_t)s * PP * CC;

    // Phase A: bulk rectangle (ready when corner fires; corner's flag
    // transitively covers every cell in it).
    if (px > 0 && py > 0) {
        wave_wait2(flags + ((px-1)*WW + (py-1)) * FSTR, lane);
        for (int x = 0; x < px; ++x)
            for (int y = 0; y < py; ++y) {
                int qp = x*WW + y;
                do_pixel8(Ub + (size_t)qp*CC, Eb + (size_t)qp*CC, cb, ar, er, hacc);
            }
    }
    // Phase B: column strip above.
    if (px > 0) {
        wave_wait2(flags + ((px-1)*WW + py) * FSTR, lane);
        for (int x = 0; x < px; ++x) {
            int qp = x*WW + py;
            do_pixel8(Ub + (size_t)qp*CC, Eb + (size_t)qp*CC, cb, ar, er, hacc);
        }
    }
    // Phase C: row strip to the left.
    if (py > 0) {
        wave_wait2(flags + (px*WW + (py-1)) * FSTR, lane);
        for (int y = 0; y < py; ++y) {
            int qp = px*WW + y;
            do_pixel8(Ub + (size_t)qp*CC, Eb + (size_t)qp*CC, cb, ar, er, hacc);
        }
    }
    // Phase D: self pixel (h==0 there -> U=0, exp(U)=1).
    {
        float ds = 0.f, tl[8];
        #pragma unroll
        for (int j = 0; j < 8; ++j) {
            float pv = er[j];
            ds += fmaxf(pv, 1.0f);
            tl[j] = fmaxf(ar[j], 0.0f) * pv;
        }
        #pragma unroll
        for (int off = 32; off; off >>= 1) ds += __shfl_xor(ds, off, 64);
        float rd = 1.0f / ds;
        #pragma unroll
        for (int j = 0; j < 8; ++j) hacc[j] += tl[j] * rd;
    }

    // Stage h; half 0 also stores Hst for the output GEMM.
    *(float4*)&hS[s][cb]       = make_float4(hacc[0],hacc[1],hacc[2],hacc[3]);
    *(float4*)&hS[s][cb + 256] = make_float4(hacc[4],hacc[5],hacc[6],hacc[7]);
    if (half == 0) {
        size_t ob = ((size_t)s * PP + cell) * CC;
        *(float4*)&Hst[ob + cb]       = make_float4(hacc[0],hacc[1],hacc[2],hacc[3]);
        *(float4*)&Hst[ob + cb + 256] = make_float4(hacc[4],hacc[5],hacc[6],hacc[7]);
    }
    __syncthreads();

    // LDS transpose hS -> hT (2-way max bank aliasing: free).
    #pragma unroll
    for (int r = 0; r < 8; ++r) {
        int idx = t + 512*r;
        hT[idx >> 3][idx & 7] = hS[idx & 7][idx >> 3];
    }
    __syncthreads();

    // Matvec mini-GEMM: U_new[c] = sum_k WhT[k][c] * h_s[k] for 8 seqs.
    // wave -> 32 channels of this half; lane>>5 -> K-half; one weight load
    // feeds 8 FMAs (one per seq).
    int c  = half * 256 + wave * 32 + (lane & 31);
    int kh = lane >> 5;
    float acc[8] = {0.f,0.f,0.f,0.f,0.f,0.f,0.f,0.f};
    const float* wp = WhT + (size_t)(kh * 256) * CC + c;
    const float* hp = &hT[kh * 256][0];
    #pragma unroll 4
    for (int k = 0; k < 256; ++k) {
        float w = wp[(size_t)k * CC];
        float4 h0 = *(const float4*)(hp + k*8);
        float4 h1 = *(const float4*)(hp + k*8 + 4);
        acc[0] += w*h0.x; acc[1] += w*h0.y; acc[2] += w*h0.z; acc[3] += w*h0.w;
        acc[4] += w*h1.x; acc[5] += w*h1.y; acc[6] += w*h1.z; acc[7] += w*h1.w;
    }
    #pragma unroll
    for (int j = 0; j < 8; ++j) acc[j] += __shfl_xor(acc[j], 32, 64);
    if (kh == 0) {
        #pragma unroll
        for (int ss = 0; ss < 8; ++ss) {
            size_t o = ((size_t)ss * PP + cell) * CC + c;
            U[o] = acc[ss]; EU[o] = expf(acc[ss]);
        }
    }

    __syncthreads();                    // all stores drained (vmcnt) pre-barrier
    if (t == 0) {
        __threadfence();                // write back past non-coherent XCD L2
        atomicAdd(flags + cell * FSTR, 1u);
    }
}

// ---------------------------------------------------------------------------
// gemm_y: Y[b][p][c] = sum_k Wo[c][k] * (sum_m Hst[m*2+b][p][k]) + 4*b_out[c]
// ---------------------------------------------------------------------------
__global__ __launch_bounds__(256) void gemm_y(
    const float* __restrict__ Wo, const float* __restrict__ Hst,
    const float* __restrict__ b_out, float* __restrict__ Y) {
    __shared__ float Ws[32][33], Hs[32][33];
    int b  = blockIdx.z;
    int c0 = blockIdx.x * 32, p0 = blockIdx.y * 32;
    int t  = threadIdx.x;
    int tx = t % 32, ty = t / 32;
    int pl = (t % 16) * 2, cl = (t / 16) * 2;
    float acc[2][2] = {{0.f,0.f},{0.f,0.f}};
    for (int k0 = 0; k0 < CC; k0 += 32) {
        #pragma unroll
        for (int r = 0; r < 4; ++r)
            Ws[ty + 8*r][tx] = Wo[(size_t)(c0 + ty + 8*r) * CC + k0 + tx];
        #pragma unroll
        for (int r = 0; r < 4; ++r) {
            int p = p0 + ty + 8*r;
            float v = 0.f;
            if (p < PP) {
                size_t base = (size_t)p * CC + k0 + tx;
                v = Hst[((size_t)(0*2 + b) * PP) * CC + base]
                  + Hst[((size_t)(1*2 + b) * PP) * CC + base]
                  + Hst[((size_t)(2*2 + b) * PP) * CC + base]
                  + Hst[((size_t)(3*2 + b) * PP) * CC + base];
            }
            Hs[tx][ty + 8*r] = v;
        }
        __syncthreads();
        #pragma unroll
        for (int k = 0; k < 32; ++k) {
            float w0 = Ws[cl][k], w1 = Ws[cl+1][k];
            float h0 = Hs[k][pl], h1 = Hs[k][pl+1];
            acc[0][0] += w0*h0; acc[0][1] += w0*h1;
            acc[1][0] += w1*h0; acc[1][1] += w1*h1;
        }
        __syncthreads();
    }
    #pragma unroll
    for (int i = 0; i < 2; ++i)
        #pragma unroll
        for (int j = 0; j < 2; ++j) {
            int cc = c0 + cl + i, p = p0 + pl + j;
            if (p < PP) Y[((size_t)b * PP + p) * CC + cc] = acc[i][j] + 4.0f * b_out[cc];
        }
}

// ---------------------------------------------------------------------------
// softmax over channels -> out[b][c][p]
// ---------------------------------------------------------------------------
__global__ __launch_bounds__(256) void softmax_out(
    const float* __restrict__ Y, float* __restrict__ out) {
    int wave = threadIdx.x >> 6, lane = threadIdx.x & 63;
    int idx = blockIdx.x * 4 + wave;
    if (idx >= BB * PP) return;
    int b = idx / PP, p = idx % PP;
    const float* y = Y + ((size_t)b * PP + p) * CC;
    float v[8];
    float mx = -3.4e38f;
    #pragma unroll
    for (int j = 0; j < 8; ++j) { v[j] = y[lane + 64*j]; mx = fmaxf(mx, v[j]); }
    #pragma unroll
    for (int off = 32; off; off >>= 1) mx = fmaxf(mx, __shfl_xor(mx, off, 64));
    float sum = 0.f;
    #pragma unroll
    for (int j = 0; j < 8; ++j) { v[j] = expf(v[j] - mx); sum += v[j]; }
    #pragma unroll
    for (int off = 32; off; off >>= 1) sum += __shfl_xor(sum, off, 64);
    float r = 1.0f / sum;
    #pragma unroll
    for (int j = 0; j < 8; ++j)
        out[((size_t)b * CC + lane + 64*j) * PP + p] = v[j] * r;
}

// ---------------------------------------------------------------------------
extern "C" void kernel_launch(void* const* d_in, const int* in_sizes, int n_in,
                              void* d_out, int out_size, void* d_ws, size_t ws_size,
                              hipStream_t stream) {
    const float* X     = (const float*)d_in[0];
    const float* Wx    = (const float*)d_in[1];
    const float* Wh    = (const float*)d_in[2];
    const float* b_in  = (const float*)d_in[3];
    const float* Wo    = (const float*)d_in[4];
    const float* b_out = (const float*)d_in[5];
    float* out = (float*)d_out;

    float* ws  = (float*)d_ws;
    float* WhT = ws;                        // 262144
    float* A   = WhT + 262144;              // 200704
    float* U   = A   + 200704;              // 802816
    float* EU  = U   + 802816;              // 802816
    float* Hst = EU  + 802816;              // 802816
    float* Y   = Hst + 802816;              // 200704
    unsigned* flags = (unsigned*)(Y + 200704);  // 196*FSTR words

    hipLaunchKernelGGL(prep, dim3(481), dim3(256), 0, stream,
                       Wx, X, b_in, Wh, A, WhT, flags);
    hipLaunchKernelGGL(rnn_dataflow, dim3(2 * PP), dim3(512), 0, stream,
                       A, WhT, U, EU, Hst, flags);
    hipLaunchKernelGGL(gemm_y, dim3(16, 7, 2), dim3(256), 0, stream, Wo, Hst, b_out, Y);
    hipLaunchKernelGGL(softmax_out, dim3(98), dim3(256), 0, stream, Y, out);
}

// Round 4
// 617.053 us; speedup vs baseline: 1.6847x; 1.6847x over previous
//
#include <hip/hip_runtime.h>
#include <hip/hip_bf16.h>

#define BB 2
#define CC 512
#define HH 14
#define WW 14
#define PP 196
#define NSEQ 8
#define NWORK 112        // 14 columns x 8 channel-slices
#define FSTR 16          // flag stride (uints): one cache line per cell

// ---------------------------------------------------------------------------
// prep: gemm_a (224 WGs) + transpose_wh (256 WGs) + flag zero (1 WG)
// ---------------------------------------------------------------------------
__global__ __launch_bounds__(256) void prep(
    const float* __restrict__ Wx, const float* __restrict__ X,
    const float* __restrict__ b_in, const float* __restrict__ Wh,
    float* __restrict__ A, float* __restrict__ WhT,
    unsigned* __restrict__ uflag, unsigned* __restrict__ hflag) {
    __shared__ float Ws[32][33], Xs[32][33];
    int bid = blockIdx.x;
    int t = threadIdx.x;
    if (bid < 224) {
        int z = bid / 112, rem = bid % 112;
        int c0 = (rem % 16) * 32, p0 = (rem / 16) * 32;
        int tx = t % 32, ty = t / 32;
        int pl = (t % 16) * 2, cl = (t / 16) * 2;
        float acc[2][2] = {{0.f,0.f},{0.f,0.f}};
        for (int k0 = 0; k0 < CC; k0 += 32) {
            #pragma unroll
            for (int r = 0; r < 4; ++r)
                Ws[ty + 8*r][tx] = Wx[(size_t)(c0 + ty + 8*r) * CC + k0 + tx];
            #pragma unroll
            for (int r = 0; r < 4; ++r) {
                int p = p0 + tx, k = k0 + ty + 8*r;
                Xs[ty + 8*r][tx] = (p < PP) ? X[((size_t)z * CC + k) * PP + p] : 0.f;
            }
            __syncthreads();
            #pragma unroll
            for (int k = 0; k < 32; ++k) {
                float w0 = Ws[cl][k], w1 = Ws[cl+1][k];
                float x0 = Xs[k][pl], x1 = Xs[k][pl+1];
                acc[0][0] += w0*x0; acc[0][1] += w0*x1;
                acc[1][0] += w1*x0; acc[1][1] += w1*x1;
            }
            __syncthreads();
        }
        #pragma unroll
        for (int i = 0; i < 2; ++i)
            #pragma unroll
            for (int j = 0; j < 2; ++j) {
                int c = c0 + cl + i, p = p0 + pl + j;
                if (p < PP) A[((size_t)z * PP + p) * CC + c] = acc[i][j] + b_in[c];
            }
    } else if (bid < 480) {
        int tid = bid - 224;
        int c0 = (tid % 16) * 32, k0 = (tid / 16) * 32;
        int tx = t % 32, ty = t / 32;
        #pragma unroll
        for (int r = 0; r < 4; ++r)
            Ws[ty + 8*r][tx] = Wh[(size_t)(c0 + ty + 8*r) * CC + k0 + tx];
        __syncthreads();
        #pragma unroll
        for (int r = 0; r < 4; ++r)
            WhT[(size_t)(k0 + ty + 8*r) * CC + c0 + tx] = Ws[tx][ty + 8*r];
    } else {
        if (t < PP) { uflag[t * FSTR] = 0u; hflag[t * FSTR] = 0u; }
    }
}

// ---------------------------------------------------------------------------
// wave-level flag wait (fast-path plain read; fallback device-scope RMW poll)
// ---------------------------------------------------------------------------
__device__ __forceinline__ void wait_flag(unsigned* f, int lane, unsigned want) {
    unsigned r = 0;
    if (lane == 0) r = *(volatile unsigned*)f;
    r = (unsigned)__shfl((int)r, 0, 64);
    while (r < want) {
        __builtin_amdgcn_s_sleep(2);
        if (lane == 0) r = atomicAdd(f, 0u);
        r = (unsigned)__shfl((int)r, 0, 64);
    }
    asm volatile("" ::: "memory");
}

// ---------------------------------------------------------------------------
// One kernel, two roles:
//   blockIdx 0..111   : persistent matvec workers (weights in VGPRs)
//   blockIdx 112..307 : per-cell window WGs (wave = seq)
// ---------------------------------------------------------------------------
__global__ __launch_bounds__(512, 2) void rnn_dataflow(
    const float* __restrict__ A, const float* __restrict__ WhT,
    float* __restrict__ U, float* __restrict__ h_t,
    float* __restrict__ Hst, unsigned* __restrict__ uflag,
    unsigned* __restrict__ hflag) {
    __shared__ float hT[CC][12];     // h transposed [k][s], row 48B (bank-spread)
    __shared__ float ured[64][8];
    int bid = blockIdx.x;
    int t = threadIdx.x;

    if (bid < NWORK) {
        // ================= persistent worker =================
        int px = bid >> 3, w = bid & 7;
        int ksub = t & 31, quad = t >> 5;       // k-interleave 32, 16 c-quads
        int c0 = w * 64 + quad * 4;
        // one-time: slice of WhT into registers: wreg[ci][j] = WhT[ksub+32j][c0+ci]
        float wreg[4][16];
        #pragma unroll
        for (int ci = 0; ci < 4; ++ci)
            #pragma unroll
            for (int j = 0; j < 16; ++j)
                wreg[ci][j] = WhT[(size_t)(ksub + 32*j) * CC + c0 + ci];
        __builtin_amdgcn_s_setprio(1);          // critical-path waves win issue

        for (int py = 0; py < WW; ++py) {
            int cell = px * WW + py;
            if (t == 0) {
                unsigned r = *(volatile unsigned*)(hflag + cell * FSTR);
                while (r == 0u) {
                    __builtin_amdgcn_s_sleep(2);
                    r = atomicAdd(hflag + cell * FSTR, 0u);
                }
            }
            __syncthreads();
            asm volatile("" ::: "memory");
            if (cell == PP - 1) break;          // U(13,13) has no consumer

            // stage h_t[cell][k][8] -> hT[k][0..7]
            const float* hp = h_t + (size_t)cell * (CC * 8);
            float4 v0 = *(const float4*)(hp + t*8);
            float4 v1 = *(const float4*)(hp + t*8 + 4);
            *(float4*)&hT[t][0] = v0;
            *(float4*)&hT[t][4] = v1;
            __syncthreads();

            float acc[4][8];
            #pragma unroll
            for (int ci = 0; ci < 4; ++ci)
                #pragma unroll
                for (int ss = 0; ss < 8; ++ss) acc[ci][ss] = 0.f;
            #pragma unroll 4
            for (int j = 0; j < 16; ++j) {
                int k = ksub + 32*j;
                float4 h0 = *(const float4*)&hT[k][0];
                float4 h1 = *(const float4*)&hT[k][4];
                float hh[8] = {h0.x,h0.y,h0.z,h0.w,h1.x,h1.y,h1.z,h1.w};
                #pragma unroll
                for (int ci = 0; ci < 4; ++ci) {
                    float wv = wreg[ci][j];
                    #pragma unroll
                    for (int ss = 0; ss < 8; ++ss) acc[ci][ss] += wv * hh[ss];
                }
            }
            // reduce over the 32 k-lanes
            #pragma unroll
            for (int off = 1; off < 32; off <<= 1)
                #pragma unroll
                for (int ci = 0; ci < 4; ++ci)
                    #pragma unroll
                    for (int ss = 0; ss < 8; ++ss)
                        acc[ci][ss] += __shfl_xor(acc[ci][ss], off, 64);
            if (ksub == 0)
                #pragma unroll
                for (int ci = 0; ci < 4; ++ci)
                    #pragma unroll
                    for (int ss = 0; ss < 8; ++ss)
                        ured[quad*4 + ci][ss] = acc[ci][ss];
            __syncthreads();
            {   // coalesced publish: thread t -> (s = t>>6, c = t&63)
                int s = t >> 6, cl = t & 63;
                U[((size_t)s * PP + cell) * CC + w*64 + cl] = ured[cl][s];
            }
            __syncthreads();                    // drain stores (vmcnt) pre-fence
            if (t == 0) { __threadfence(); atomicAdd(uflag + cell * FSTR, 1u); }
        }
    } else {
        // ================= per-cell window WG =================
        int cell = bid - NWORK;
        int px = cell / WW, py = cell % WW;
        int wave = t >> 6, lane = t & 63;
        int s = wave, m = s >> 1, b = s & 1;
        int fi = (m & 2) ? (HH-1-px) : px;
        int fj = (m & 1) ? (WW-1-py) : py;
        int cb = lane * 4;

        const float* acur = A + ((size_t)b * PP + fi * WW + fj) * CC;
        float4 a0 = *(const float4*)(acur + cb);
        float4 a1 = *(const float4*)(acur + cb + 256);
        float ar[8] = {a0.x,a0.y,a0.z,a0.w,a1.x,a1.y,a1.z,a1.w};
        float er[8];
        #pragma unroll
        for (int j = 0; j < 8; ++j) er[j] = __expf(ar[j]);
        float hacc[8] = {0.f,0.f,0.f,0.f,0.f,0.f,0.f,0.f};

        const float* Ub = U + (size_t)s * PP * CC;
        for (int x = 0; x <= px; ++x) {
            int ylim = (x == px) ? py : py + 1;     // self handled separately
            for (int y = 0; y < ylim; ++y) {
                int q = x * WW + y;
                wait_flag(uflag + q * FSTR, lane, 8u);
                const float4* up = (const float4*)(Ub + (size_t)q * CC + cb);
                float4 u0 = up[0], u1 = up[64];
                float uu[8] = {u0.x,u0.y,u0.z,u0.w,u1.x,u1.y,u1.z,u1.w};
                float ds = 0.f, tl[8];
                #pragma unroll
                for (int j = 0; j < 8; ++j) {
                    float sv = ar[j] + uu[j];            // a + U
                    float pv = er[j] * __expf(uu[j]);    // exp(a+U)
                    ds += fmaxf(pv, 1.0f);               // exp(relu(a+U))
                    tl[j] = fmaxf(sv, 0.0f) * pv;        // z * exp(z)
                }
                #pragma unroll
                for (int off = 32; off; off >>= 1) ds += __shfl_xor(ds, off, 64);
                float rd = 1.0f / ds;
                #pragma unroll
                for (int j = 0; j < 8; ++j) hacc[j] += tl[j] * rd;
            }
        }
        {   // self pixel: U=0, exp(U)=1
            float ds = 0.f, tl[8];
            #pragma unroll
            for (int j = 0; j < 8; ++j) {
                float pv = er[j];
                ds += fmaxf(pv, 1.0f);
                tl[j] = fmaxf(ar[j], 0.0f) * pv;
            }
            #pragma unroll
            for (int off = 32; off; off >>= 1) ds += __shfl_xor(ds, off, 64);
            float rd = 1.0f / ds;
            #pragma unroll
            for (int j = 0; j < 8; ++j) hacc[j] += tl[j] * rd;
        }

        // publish h (k-major x 8 seqs for the workers) + Hst (c-major for gemm_y)
        float* hp = h_t + (size_t)cell * (CC * 8);
        #pragma unroll
        for (int j = 0; j < 4; ++j) {
            hp[(cb + j) * 8 + s]       = hacc[j];
            hp[(cb + 256 + j) * 8 + s] = hacc[4 + j];
        }
        size_t ob = ((size_t)s * PP + cell) * CC;
        *(float4*)&Hst[ob + cb]       = make_float4(hacc[0],hacc[1],hacc[2],hacc[3]);
        *(float4*)&Hst[ob + cb + 256] = make_float4(hacc[4],hacc[5],hacc[6],hacc[7]);
        __syncthreads();
        if (t == 0) { __threadfence(); atomicExch(hflag + cell * FSTR, 1u); }
    }
}

// ---------------------------------------------------------------------------
// gemm_y: Y[b][p][c] = sum_k Wo[c][k] * (sum_m Hst[m*2+b][p][k]) + 4*b_out[c]
// ---------------------------------------------------------------------------
__global__ __launch_bounds__(256) void gemm_y(
    const float* __restrict__ Wo, const float* __restrict__ Hst,
    const float* __restrict__ b_out, float* __restrict__ Y) {
    __shared__ float Ws[32][33], Hs[32][33];
    int b  = blockIdx.z;
    int c0 = blockIdx.x * 32, p0 = blockIdx.y * 32;
    int t  = threadIdx.x;
    int tx = t % 32, ty = t / 32;
    int pl = (t % 16) * 2, cl = (t / 16) * 2;
    float acc[2][2] = {{0.f,0.f},{0.f,0.f}};
    for (int k0 = 0; k0 < CC; k0 += 32) {
        #pragma unroll
        for (int r = 0; r < 4; ++r)
            Ws[ty + 8*r][tx] = Wo[(size_t)(c0 + ty + 8*r) * CC + k0 + tx];
        #pragma unroll
        for (int r = 0; r < 4; ++r) {
            int p = p0 + ty + 8*r;
            float v = 0.f;
            if (p < PP) {
                size_t base = (size_t)p * CC + k0 + tx;
                v = Hst[((size_t)(0*2 + b) * PP) * CC + base]
                  + Hst[((size_t)(1*2 + b) * PP) * CC + base]
                  + Hst[((size_t)(2*2 + b) * PP) * CC + base]
                  + Hst[((size_t)(3*2 + b) * PP) * CC + base];
            }
            Hs[tx][ty + 8*r] = v;
        }
        __syncthreads();
        #pragma unroll
        for (int k = 0; k < 32; ++k) {
            float w0 = Ws[cl][k], w1 = Ws[cl+1][k];
            float h0 = Hs[k][pl], h1 = Hs[k][pl+1];
            acc[0][0] += w0*h0; acc[0][1] += w0*h1;
            acc[1][0] += w1*h0; acc[1][1] += w1*h1;
        }
        __syncthreads();
    }
    #pragma unroll
    for (int i = 0; i < 2; ++i)
        #pragma unroll
        for (int j = 0; j < 2; ++j) {
            int cc = c0 + cl + i, p = p0 + pl + j;
            if (p < PP) Y[((size_t)b * PP + p) * CC + cc] = acc[i][j] + 4.0f * b_out[cc];
        }
}

// ---------------------------------------------------------------------------
// softmax over channels -> out[b][c][p]
// ---------------------------------------------------------------------------
__global__ __launch_bounds__(256) void softmax_out(
    const float* __restrict__ Y, float* __restrict__ out) {
    int wave = threadIdx.x >> 6, lane = threadIdx.x & 63;
    int idx = blockIdx.x * 4 + wave;
    if (idx >= BB * PP) return;
    int b = idx / PP, p = idx % PP;
    const float* y = Y + ((size_t)b * PP + p) * CC;
    float v[8];
    float mx = -3.4e38f;
    #pragma unroll
    for (int j = 0; j < 8; ++j) { v[j] = y[lane + 64*j]; mx = fmaxf(mx, v[j]); }
    #pragma unroll
    for (int off = 32; off; off >>= 1) mx = fmaxf(mx, __shfl_xor(mx, off, 64));
    float sum = 0.f;
    #pragma unroll
    for (int j = 0; j < 8; ++j) { v[j] = expf(v[j] - mx); sum += v[j]; }
    #pragma unroll
    for (int off = 32; off; off >>= 1) sum += __shfl_xor(sum, off, 64);
    float r = 1.0f / sum;
    #pragma unroll
    for (int j = 0; j < 8; ++j)
        out[((size_t)b * CC + lane + 64*j) * PP + p] = v[j] * r;
}

// ---------------------------------------------------------------------------
extern "C" void kernel_launch(void* const* d_in, const int* in_sizes, int n_in,
                              void* d_out, int out_size, void* d_ws, size_t ws_size,
                              hipStream_t stream) {
    const float* X     = (const float*)d_in[0];
    const float* Wx    = (const float*)d_in[1];
    const float* Wh    = (const float*)d_in[2];
    const float* b_in  = (const float*)d_in[3];
    const float* Wo    = (const float*)d_in[4];
    const float* b_out = (const float*)d_in[5];
    float* out = (float*)d_out;

    float* ws  = (float*)d_ws;
    float* WhT = ws;                        // 262144
    float* A   = WhT + 262144;              // 200704
    float* U   = A   + 200704;              // 802816  [s][cell][c]
    float* h_t = U   + 802816;              // 802816  [cell][k][8]
    float* Hst = h_t + 802816;              // 802816  [s][cell][c]
    float* Y   = Hst + 802816;              // 200704
    unsigned* uflag = (unsigned*)(Y + 200704);      // 196*FSTR
    unsigned* hflag = uflag + PP * FSTR;            // 196*FSTR

    hipLaunchKernelGGL(prep, dim3(481), dim3(256), 0, stream,
                       Wx, X, b_in, Wh, A, WhT, uflag, hflag);
    hipLaunchKernelGGL(rnn_dataflow, dim3(NWORK + PP), dim3(512), 0, stream,
                       A, WhT, U, h_t, Hst, uflag, hflag);
    hipLaunchKernelGGL(gemm_y, dim3(16, 7, 2), dim3(256), 0, stream, Wo, Hst, b_out, Y);
    hipLaunchKernelGGL(softmax_out, dim3(98), dim3(256), 0, stream, Y, out);
}